// Round 3
// baseline (373.561 us; speedup 1.0000x reference)
//
#include <hip/hip_runtime.h>

typedef unsigned short u16;
typedef short vshort8 __attribute__((ext_vector_type(8)));
typedef __bf16 vbf16x8 __attribute__((ext_vector_type(8)));
typedef float vf32x4 __attribute__((ext_vector_type(4)));
typedef float vf32x16 __attribute__((ext_vector_type(16)));

__device__ __forceinline__ u16 f2bf(float f) {
  unsigned u = __builtin_bit_cast(unsigned, f);
  u += 0x7FFFu + ((u >> 16) & 1u);
  return (u16)(u >> 16);
}

__device__ __forceinline__ unsigned cvtpk(float lo, float hi) {
  unsigned r;
  asm("v_cvt_pk_bf16_f32 %0, %1, %2" : "=v"(r) : "v"(lo), "v"(hi));
  return r;
}

__device__ __forceinline__ vf32x4 mfma_bf16(vshort8 a, vshort8 b, vf32x4 c) {
  return __builtin_amdgcn_mfma_f32_16x16x32_bf16(
      __builtin_bit_cast(vbf16x8, a), __builtin_bit_cast(vbf16x8, b), c, 0, 0, 0);
}

__device__ __forceinline__ vf32x16 mfma32(vshort8 a, vshort8 b, vf32x16 c) {
  return __builtin_amdgcn_mfma_f32_32x32x16_bf16(
      __builtin_bit_cast(vbf16x8, a), __builtin_bit_cast(vbf16x8, b), c, 0, 0, 0);
}

__device__ __forceinline__ void gload16(const void* g, void* l) {
  __builtin_amdgcn_global_load_lds(
      (const __attribute__((address_space(1))) void*)g,
      (__attribute__((address_space(3))) void*)l, 16, 0, 0);
}

// ---------------- fp32 -> bf16 elementwise (1 or 2 tensors via blockIdx.y) ----------------
__global__ __launch_bounds__(256) void cvtk2(const float* __restrict__ a,
                                             const float* __restrict__ b,
                                             u16* __restrict__ oa,
                                             u16* __restrict__ ob, int n4) {
  const float* in = blockIdx.y ? b : a;
  u16* out = blockIdx.y ? ob : oa;
  if (in == nullptr) return;
  int idx = blockIdx.x * 256 + threadIdx.x;
  int stride = gridDim.x * 256;
  for (int i = idx; i < n4; i += stride) {
    float4 v = ((const float4*)in)[i];
    unsigned lo = (unsigned)f2bf(v.x) | ((unsigned)f2bf(v.y) << 16);
    unsigned hi = (unsigned)f2bf(v.z) | ((unsigned)f2bf(v.w) << 16);
    uint2 o; o.x = lo; o.y = hi;
    *(uint2*)&out[(size_t)i * 4] = o;
  }
}

// ---------------- weight transpose + cvt: W[k][n] f32 -> Wt[n][k] bf16 (4 via z) ----------------
__global__ __launch_bounds__(256) void wtrans4(const float* __restrict__ w0,
                                               const float* __restrict__ w1,
                                               const float* __restrict__ w2,
                                               const float* __restrict__ w3,
                                               u16* __restrict__ o0, u16* __restrict__ o1,
                                               u16* __restrict__ o2, u16* __restrict__ o3) {
  int z = blockIdx.z;
  const float* W = z == 0 ? w0 : z == 1 ? w1 : z == 2 ? w2 : w3;
  u16* Wt = z == 0 ? o0 : z == 1 ? o1 : z == 2 ? o2 : o3;
  __shared__ u16 tile[64][72];
  int t = threadIdx.x;
  int n0 = blockIdx.x * 64, k0 = blockIdx.y * 64;
#pragma unroll
  for (int it = 0; it < 4; ++it) {
    int cid = it * 256 + t;
    int r = cid >> 4, c4 = cid & 15;
    float4 v = *(const float4*)&W[(k0 + r) * 1024 + n0 + c4 * 4];
    u16* d = &tile[r][c4 * 4];
    d[0] = f2bf(v.x); d[1] = f2bf(v.y); d[2] = f2bf(v.z); d[3] = f2bf(v.w);
  }
  __syncthreads();
#pragma unroll
  for (int it = 0; it < 4; ++it) {
    int cid = it * 256 + t;
    int rn = cid >> 4, c4 = cid & 15;
    unsigned lo = (unsigned)tile[c4 * 4 + 0][rn] | ((unsigned)tile[c4 * 4 + 1][rn] << 16);
    unsigned hi = (unsigned)tile[c4 * 4 + 2][rn] | ((unsigned)tile[c4 * 4 + 3][rn] << 16);
    uint2 o; o.x = lo; o.y = hi;
    *(uint2*)&Wt[(n0 + rn) * 1024 + k0 + c4 * 4] = o;
  }
}

// ---------------- V transpose: V[b*2048+s][h*64+d] -> Vt[(bh*64+d)][s] (bf16) ----------------
__global__ __launch_bounds__(256) void vtrans(const u16* __restrict__ V,
                                              u16* __restrict__ Vt) {
  __shared__ u16 tile[64][72];
  int t = threadIdx.x;
  int s0 = blockIdx.x * 64;
  int bh = blockIdx.y, b = bh >> 4, h = bh & 15;
#pragma unroll
  for (int it = 0; it < 2; ++it) {
    int cid = it * 256 + t;
    int r = cid >> 3, c8 = cid & 7;
    vshort8 v = *(const vshort8*)&V[(size_t)(b * 2048 + s0 + r) * 1024 + h * 64 + c8 * 8];
    *(vshort8*)&tile[r][c8 * 8] = v;
  }
  __syncthreads();
#pragma unroll
  for (int it = 0; it < 2; ++it) {
    int cid = it * 256 + t;
    int rd = cid >> 3, c8 = cid & 7;
    unsigned w[4];
#pragma unroll
    for (int j = 0; j < 4; ++j) {
      unsigned lo = tile[c8 * 8 + 2 * j][rd];
      unsigned hi = tile[c8 * 8 + 2 * j + 1][rd];
      w[j] = lo | (hi << 16);
    }
    uint4 o; o.x = w[0]; o.y = w[1]; o.z = w[2]; o.w = w[3];
    *(uint4*)&Vt[(size_t)(bh * 64 + rd) * 2048 + s0 + c8 * 8] = o;
  }
}

// ---------------- bf16 GEMM: C[M,N] = (A[M,K] * Bt[N,K]^T) * oscale ----------------
template <int OUTF32>
__global__ __launch_bounds__(256) void gemm_nt(const u16* __restrict__ A,
                                               const u16* __restrict__ Bt,
                                               float* __restrict__ Cf,
                                               u16* __restrict__ Cb,
                                               int M, int N, int K, float oscale) {
  __shared__ __align__(16) u16 As[128 * 64];
  __shared__ __align__(16) u16 Bs[128 * 64];
  int t = threadIdx.x, lane = t & 63, wid = t >> 6;
  int g = lane >> 4, i16 = lane & 15;
  int n0 = blockIdx.x * 128, m0 = blockIdx.y * 128;
  int wm = wid >> 1, wn = wid & 1;

  vf32x4 acc[4][4];
#pragma unroll
  for (int a = 0; a < 4; ++a)
#pragma unroll
    for (int b = 0; b < 4; ++b) acc[a][b] = (vf32x4){0.f, 0.f, 0.f, 0.f};

  int ldsbase = (wid * 64) * 8;
  for (int kt = 0; kt < K / 64; ++kt) {
    if (kt) __syncthreads();
#pragma unroll
    for (int it = 0; it < 4; ++it) {
      int cid = it * 256 + t;
      int row = cid >> 3, c = cid & 7, sc = c ^ (row & 7);
      gload16(A + (size_t)(m0 + row) * K + kt * 64 + sc * 8, &As[it * 2048 + ldsbase]);
    }
#pragma unroll
    for (int it = 0; it < 4; ++it) {
      int cid = it * 256 + t;
      int row = cid >> 3, c = cid & 7, sc = c ^ (row & 7);
      gload16(Bt + (size_t)(n0 + row) * K + kt * 64 + sc * 8, &Bs[it * 2048 + ldsbase]);
    }
    __syncthreads();
#pragma unroll
    for (int kc = 0; kc < 2; ++kc) {
      vshort8 af[4], bf[4];
#pragma unroll
      for (int mf = 0; mf < 4; ++mf) {
        int row = wm * 64 + mf * 16 + i16;
        int ch = (kc * 4 + g) ^ (row & 7);
        af[mf] = *(const vshort8*)&As[row * 64 + ch * 8];
      }
#pragma unroll
      for (int nf = 0; nf < 4; ++nf) {
        int row = wn * 64 + nf * 16 + i16;
        int ch = (kc * 4 + g) ^ (row & 7);
        bf[nf] = *(const vshort8*)&Bs[row * 64 + ch * 8];
      }
#pragma unroll
      for (int mf = 0; mf < 4; ++mf)
#pragma unroll
        for (int nf = 0; nf < 4; ++nf)
          acc[mf][nf] = mfma_bf16(af[mf], bf[nf], acc[mf][nf]);
    }
  }
#pragma unroll
  for (int mf = 0; mf < 4; ++mf)
#pragma unroll
    for (int nf = 0; nf < 4; ++nf)
#pragma unroll
      for (int r = 0; r < 4; ++r) {
        int m = m0 + wm * 64 + mf * 16 + g * 4 + r;
        int n = n0 + wn * 64 + nf * 16 + i16;
        if (OUTF32)
          Cf[(size_t)m * N + n] = acc[mf][nf][r] * oscale;
        else
          Cb[(size_t)m * N + n] = f2bf(acc[mf][nf][r] * oscale);
      }
}

// ---------------- fused flash attention: 32 q-rows/wave, 4 waves/block, zero LDS ----------------
// Q (pre-scaled by 0.125*log2e), K: [8192,1024] bf16; Vt: [64*64,2048] bf16; O: [8192,1024] bf16
__global__ __launch_bounds__(256, 4) void attn_fwd3(const u16* __restrict__ Q,
                                                    const u16* __restrict__ K,
                                                    const u16* __restrict__ Vt,
                                                    u16* __restrict__ O) {
  int t = threadIdx.x, lane = t & 63, w = t >> 6;
  int l31 = lane & 31, hi = lane >> 5;
  int i = blockIdx.x;                    // 1024 blocks
  int bh = (i & 7) + 8 * (i >> 7);       // same-bh blocks share XCD (i%8)
  int qc = (i >> 3) & 15;                // 16 q-chunks of 128 rows
  int b = bh >> 4, h = bh & 15;

  const u16* Qbase = Q + (size_t)(b * 2048 + qc * 128 + w * 32) * 1024 + h * 64;
  const u16* Kbase = K + (size_t)(b * 2048) * 1024 + h * 64;
  const u16* Vbase = Vt + (size_t)(bh * 64) * 2048;

  // Q fragments: B-operand, q = l31, d = dc*16 + hi*8 + j
  vshort8 qf[4];
#pragma unroll
  for (int dc = 0; dc < 4; ++dc)
    qf[dc] = *(const vshort8*)&Qbase[(size_t)l31 * 1024 + dc * 16 + hi * 8];

  vf32x16 oacc[2];  // O^T: row d = crow(r,hi)+32*dm, col q = l31
#pragma unroll
  for (int dm = 0; dm < 2; ++dm)
#pragma unroll
    for (int r = 0; r < 16; ++r) oacc[dm][r] = 0.f;
  float mrun = -3.0e38f, lrun = 0.f;

  for (int kt = 0; kt < 32; ++kt) {
    __syncthreads();  // convoy: 4 waves share K/V tiles via L1
    vshort8 kf[2][4];
#pragma unroll
    for (int ks = 0; ks < 2; ++ks)
#pragma unroll
      for (int dc = 0; dc < 4; ++dc)
        kf[ks][dc] = *(const vshort8*)&Kbase[(size_t)(kt * 64 + ks * 32 + l31) * 1024 + dc * 16 + hi * 8];

    vf32x16 sacc[2];
#pragma unroll
    for (int ks = 0; ks < 2; ++ks)
#pragma unroll
      for (int r = 0; r < 16; ++r) sacc[ks][r] = 0.f;

    __builtin_amdgcn_s_setprio(1);
#pragma unroll
    for (int dc = 0; dc < 4; ++dc)
#pragma unroll
      for (int ks = 0; ks < 2; ++ks)
        sacc[ks] = mfma32(kf[ks][dc], qf[dc], sacc[ks]);
    __builtin_amdgcn_s_setprio(0);

    // tree max over 32 values
    float tm[8];
#pragma unroll
    for (int r = 0; r < 8; ++r)
      tm[r] = fmaxf(fmaxf(sacc[0][r], sacc[0][r + 8]), fmaxf(sacc[1][r], sacc[1][r + 8]));
#pragma unroll
    for (int r = 0; r < 4; ++r) tm[r] = fmaxf(tm[r], tm[r + 4]);
    float pmax = fmaxf(fmaxf(tm[0], tm[1]), fmaxf(tm[2], tm[3]));
    pmax = fmaxf(pmax, __shfl_xor(pmax, 32));

    if (pmax > mrun + 8.f) {  // defer-max
      float al = exp2f(mrun - pmax);
      lrun *= al;
#pragma unroll
      for (int dm = 0; dm < 2; ++dm)
#pragma unroll
        for (int r = 0; r < 16; ++r) oacc[dm][r] *= al;
      mrun = pmax;
    }
    float mm = mrun;

    // exp2 + pack to bf16 pairs + partial sums (4-way tree)
    unsigned pk[2][8];
    float s0 = 0.f, s1 = 0.f, s2 = 0.f, s3 = 0.f;
#pragma unroll
    for (int ks = 0; ks < 2; ++ks)
#pragma unroll
      for (int u = 0; u < 8; ++u) {
        float p0 = exp2f(sacc[ks][2 * u] - mm);
        float p1 = exp2f(sacc[ks][2 * u + 1] - mm);
        pk[ks][u] = cvtpk(p0, p1);
        if (u & 1) { s0 += p0; s1 += p1; } else { s2 += p0; s3 += p1; }
      }
    float ssum = (s0 + s1) + (s2 + s3);
    ssum += __shfl_xor(ssum, 32);
    lrun += ssum;

    // V^T fragments: row d = dm*32 + l31, k = kt*64 + s*16 + hi*8 + j
    vshort8 vtf[2][4];
#pragma unroll
    for (int dm = 0; dm < 2; ++dm)
#pragma unroll
      for (int s = 0; s < 4; ++s)
        vtf[dm][s] = *(const vshort8*)&Vbase[(size_t)(dm * 32 + l31) * 2048 + kt * 64 + s * 16 + hi * 8];

    // in-register P redistribution -> B-operand fragments pb[s]
    vshort8 pb[4];
#pragma unroll
    for (int s = 0; s < 4; ++s) {
      const int ks = s >> 1, s1b = s & 1;
      unsigned wA0 = pk[ks][4 * s1b + 0], wA1 = pk[ks][4 * s1b + 1];
      unsigned wB0 = pk[ks][4 * s1b + 2], wB1 = pk[ks][4 * s1b + 3];
      unsigned sA0 = hi ? wB0 : wA0, sA1 = hi ? wB1 : wA1;
      unsigned sd0 = hi ? wA0 : wB0, sd1 = hi ? wA1 : wB1;
      unsigned rv0 = __shfl_xor((int)sd0, 32), rv1 = __shfl_xor((int)sd1, 32);
      uint4 wv;
      wv.x = hi ? rv0 : sA0; wv.y = hi ? rv1 : sA1;
      wv.z = hi ? sA0 : rv0; wv.w = hi ? sA1 : rv1;
      pb[s] = __builtin_bit_cast(vshort8, wv);
    }

    __builtin_amdgcn_s_setprio(1);
#pragma unroll
    for (int s = 0; s < 4; ++s)
#pragma unroll
      for (int dm = 0; dm < 2; ++dm)
        oacc[dm] = mfma32(vtf[dm][s], pb[s], oacc[dm]);
    __builtin_amdgcn_s_setprio(0);
  }

  // epilogue: O[q][d], q lane-local, d = dm*32 + 8u + 4hi + (0..3)
  float inv = 1.f / lrun;
  size_t qrow = (size_t)(b * 2048 + qc * 128 + w * 32 + l31);
#pragma unroll
  for (int dm = 0; dm < 2; ++dm)
#pragma unroll
    for (int u = 0; u < 4; ++u) {
      unsigned w0 = cvtpk(oacc[dm][4 * u + 0] * inv, oacc[dm][4 * u + 1] * inv);
      unsigned w1 = cvtpk(oacc[dm][4 * u + 2] * inv, oacc[dm][4 * u + 3] * inv);
      uint2 o; o.x = w0; o.y = w1;
      *(uint2*)&O[qrow * 1024 + h * 64 + dm * 32 + 8 * u + 4 * hi] = o;
    }
}

extern "C" void kernel_launch(void* const* d_in, const int* in_sizes, int n_in,
                              void* d_out, int out_size, void* d_ws, size_t ws_size,
                              hipStream_t stream) {
  const float* q  = (const float*)d_in[0];
  const float* k  = (const float*)d_in[1];
  const float* v  = (const float*)d_in[2];
  const float* wq = (const float*)d_in[3];
  const float* wk = (const float*)d_in[4];
  const float* wv = (const float*)d_in[5];
  const float* wo = (const float*)d_in[6];
  float* out = (float*)d_out;

  const int M = 8192, D = 1024;
  u16* Qb = (u16*)d_out;                // Q,K (bf16) parked in d_out (32MB)
  u16* Kb = Qb + (size_t)M * D;
  u16* xb  = (u16*)d_ws;                // staging / attn-out
  u16* Vb  = xb + (size_t)M * D;
  u16* Vtg = Vb + (size_t)M * D;        // doubles as xk staging before vtrans
  u16* wqt = Vtg + (size_t)M * D;
  u16* wkt = wqt + (size_t)D * D;
  u16* wvt = wkt + (size_t)D * D;
  u16* wot = wvt + (size_t)D * D;

  dim3 blk(256);
  wtrans4<<<dim3(16, 16, 4), blk, 0, stream>>>(wq, wk, wv, wo, wqt, wkt, wvt, wot);

  const float QSCALE = 0.125f * 1.44269504088896f;  // 1/sqrt(64) * log2(e)
  int n4 = M * D / 4;
  dim3 ggemm(8, 64);
  // convert q->xb and k->Vtg(as xk) in one launch
  cvtk2<<<dim3(1024, 2), blk, 0, stream>>>(q, k, xb, Vtg, n4);
  gemm_nt<0><<<ggemm, blk, 0, stream>>>(xb, wqt, nullptr, Qb, M, D, D, QSCALE);
  gemm_nt<0><<<ggemm, blk, 0, stream>>>(Vtg, wkt, nullptr, Kb, M, D, D, 1.0f);
  cvtk2<<<dim3(1024, 1), blk, 0, stream>>>(v, nullptr, xb, nullptr, n4);
  gemm_nt<0><<<ggemm, blk, 0, stream>>>(xb, wvt, nullptr, Vb, M, D, D, 1.0f);

  vtrans<<<dim3(32, 64), blk, 0, stream>>>(Vb, Vtg);
  attn_fwd3<<<dim3(1024), blk, 0, stream>>>(Qb, Kb, Vtg, xb /* -> attn out */);
  gemm_nt<1><<<ggemm, blk, 0, stream>>>(xb, wot, out, nullptr, M, D, D, 1.0f);
}

// Round 5
// 265.356 us; speedup vs baseline: 1.4078x; 1.4078x over previous
//
#include <hip/hip_runtime.h>

typedef unsigned short u16;
typedef short vshort8 __attribute__((ext_vector_type(8)));
typedef __bf16 vbf16x8 __attribute__((ext_vector_type(8)));
typedef float vf32x4 __attribute__((ext_vector_type(4)));
typedef float vf32x16 __attribute__((ext_vector_type(16)));

__device__ __forceinline__ u16 f2bf(float f) {
  unsigned u = __builtin_bit_cast(unsigned, f);
  u += 0x7FFFu + ((u >> 16) & 1u);
  return (u16)(u >> 16);
}

__device__ __forceinline__ unsigned cvtpk(float lo, float hi) {
  unsigned r;
  asm("v_cvt_pk_bf16_f32 %0, %1, %2" : "=v"(r) : "v"(lo), "v"(hi));
  return r;
}

// y[lane] = x[lane^32]  (proven-correct DS-pipe path)
__device__ __forceinline__ float swap32f(float x) {
  return __shfl_xor(x, 32);
}

__device__ __forceinline__ vf32x4 mfma_bf16(vshort8 a, vshort8 b, vf32x4 c) {
  return __builtin_amdgcn_mfma_f32_16x16x32_bf16(
      __builtin_bit_cast(vbf16x8, a), __builtin_bit_cast(vbf16x8, b), c, 0, 0, 0);
}

__device__ __forceinline__ vf32x16 mfma32(vshort8 a, vshort8 b, vf32x16 c) {
  return __builtin_amdgcn_mfma_f32_32x32x16_bf16(
      __builtin_bit_cast(vbf16x8, a), __builtin_bit_cast(vbf16x8, b), c, 0, 0, 0);
}

__device__ __forceinline__ void gload16(const void* g, void* l) {
  __builtin_amdgcn_global_load_lds(
      (const __attribute__((address_space(1))) void*)g,
      (__attribute__((address_space(3))) void*)l, 16, 0, 0);
}

// ---------------- fp32 -> bf16 elementwise (1 or 2 tensors via blockIdx.y) ----------------
__global__ __launch_bounds__(256) void cvtk2(const float* __restrict__ a,
                                             const float* __restrict__ b,
                                             u16* __restrict__ oa,
                                             u16* __restrict__ ob, int n4) {
  const float* in = blockIdx.y ? b : a;
  u16* out = blockIdx.y ? ob : oa;
  if (in == nullptr) return;
  int idx = blockIdx.x * 256 + threadIdx.x;
  int stride = gridDim.x * 256;
  for (int i = idx; i < n4; i += stride) {
    float4 v = ((const float4*)in)[i];
    unsigned lo = (unsigned)f2bf(v.x) | ((unsigned)f2bf(v.y) << 16);
    unsigned hi = (unsigned)f2bf(v.z) | ((unsigned)f2bf(v.w) << 16);
    uint2 o; o.x = lo; o.y = hi;
    *(uint2*)&out[(size_t)i * 4] = o;
  }
}

// ---------------- weight transpose + cvt: W[k][n] f32 -> Wt[n][k] bf16 (4 via z) ----------------
__global__ __launch_bounds__(256) void wtrans4(const float* __restrict__ w0,
                                               const float* __restrict__ w1,
                                               const float* __restrict__ w2,
                                               const float* __restrict__ w3,
                                               u16* __restrict__ o0, u16* __restrict__ o1,
                                               u16* __restrict__ o2, u16* __restrict__ o3) {
  int z = blockIdx.z;
  const float* W = z == 0 ? w0 : z == 1 ? w1 : z == 2 ? w2 : w3;
  u16* Wt = z == 0 ? o0 : z == 1 ? o1 : z == 2 ? o2 : o3;
  __shared__ u16 tile[64][72];
  int t = threadIdx.x;
  int n0 = blockIdx.x * 64, k0 = blockIdx.y * 64;
#pragma unroll
  for (int it = 0; it < 4; ++it) {
    int cid = it * 256 + t;
    int r = cid >> 4, c4 = cid & 15;
    float4 v = *(const float4*)&W[(k0 + r) * 1024 + n0 + c4 * 4];
    u16* d = &tile[r][c4 * 4];
    d[0] = f2bf(v.x); d[1] = f2bf(v.y); d[2] = f2bf(v.z); d[3] = f2bf(v.w);
  }
  __syncthreads();
#pragma unroll
  for (int it = 0; it < 4; ++it) {
    int cid = it * 256 + t;
    int rn = cid >> 4, c4 = cid & 15;
    unsigned lo = (unsigned)tile[c4 * 4 + 0][rn] | ((unsigned)tile[c4 * 4 + 1][rn] << 16);
    unsigned hi = (unsigned)tile[c4 * 4 + 2][rn] | ((unsigned)tile[c4 * 4 + 3][rn] << 16);
    uint2 o; o.x = lo; o.y = hi;
    *(uint2*)&Wt[(n0 + rn) * 1024 + k0 + c4 * 4] = o;
  }
}

// ---------------- V transpose: V[b*2048+s][h*64+d] -> Vt[(bh*64+d)][s] (bf16) ----------------
__global__ __launch_bounds__(256) void vtrans(const u16* __restrict__ V,
                                              u16* __restrict__ Vt) {
  __shared__ u16 tile[64][72];
  int t = threadIdx.x;
  int s0 = blockIdx.x * 64;
  int bh = blockIdx.y, b = bh >> 4, h = bh & 15;
#pragma unroll
  for (int it = 0; it < 2; ++it) {
    int cid = it * 256 + t;
    int r = cid >> 3, c8 = cid & 7;
    vshort8 v = *(const vshort8*)&V[(size_t)(b * 2048 + s0 + r) * 1024 + h * 64 + c8 * 8];
    *(vshort8*)&tile[r][c8 * 8] = v;
  }
  __syncthreads();
#pragma unroll
  for (int it = 0; it < 2; ++it) {
    int cid = it * 256 + t;
    int rd = cid >> 3, c8 = cid & 7;
    unsigned w[4];
#pragma unroll
    for (int j = 0; j < 4; ++j) {
      unsigned lo = tile[c8 * 8 + 2 * j][rd];
      unsigned hi = tile[c8 * 8 + 2 * j + 1][rd];
      w[j] = lo | (hi << 16);
    }
    uint4 o; o.x = w[0]; o.y = w[1]; o.z = w[2]; o.w = w[3];
    *(uint4*)&Vt[(size_t)(bh * 64 + rd) * 2048 + s0 + c8 * 8] = o;
  }
}

// ---------------- bf16 GEMM: C[M,N] = (A[M,K] * Bt[N,K]^T) * oscale ----------------
template <int OUTF32>
__global__ __launch_bounds__(256) void gemm_nt(const u16* __restrict__ A,
                                               const u16* __restrict__ Bt,
                                               float* __restrict__ Cf,
                                               u16* __restrict__ Cb,
                                               int M, int N, int K, float oscale) {
  __shared__ __align__(16) u16 As[128 * 64];
  __shared__ __align__(16) u16 Bs[128 * 64];
  int t = threadIdx.x, lane = t & 63, wid = t >> 6;
  int g = lane >> 4, i16 = lane & 15;
  int n0 = blockIdx.x * 128, m0 = blockIdx.y * 128;
  int wm = wid >> 1, wn = wid & 1;

  vf32x4 acc[4][4];
#pragma unroll
  for (int a = 0; a < 4; ++a)
#pragma unroll
    for (int b = 0; b < 4; ++b) acc[a][b] = (vf32x4){0.f, 0.f, 0.f, 0.f};

  int ldsbase = (wid * 64) * 8;
  for (int kt = 0; kt < K / 64; ++kt) {
    if (kt) __syncthreads();
#pragma unroll
    for (int it = 0; it < 4; ++it) {
      int cid = it * 256 + t;
      int row = cid >> 3, c = cid & 7, sc = c ^ (row & 7);
      gload16(A + (size_t)(m0 + row) * K + kt * 64 + sc * 8, &As[it * 2048 + ldsbase]);
    }
#pragma unroll
    for (int it = 0; it < 4; ++it) {
      int cid = it * 256 + t;
      int row = cid >> 3, c = cid & 7, sc = c ^ (row & 7);
      gload16(Bt + (size_t)(n0 + row) * K + kt * 64 + sc * 8, &Bs[it * 2048 + ldsbase]);
    }
    __syncthreads();
#pragma unroll
    for (int kc = 0; kc < 2; ++kc) {
      vshort8 af[4], bf[4];
#pragma unroll
      for (int mf = 0; mf < 4; ++mf) {
        int row = wm * 64 + mf * 16 + i16;
        int ch = (kc * 4 + g) ^ (row & 7);
        af[mf] = *(const vshort8*)&As[row * 64 + ch * 8];
      }
#pragma unroll
      for (int nf = 0; nf < 4; ++nf) {
        int row = wn * 64 + nf * 16 + i16;
        int ch = (kc * 4 + g) ^ (row & 7);
        bf[nf] = *(const vshort8*)&Bs[row * 64 + ch * 8];
      }
#pragma unroll
      for (int mf = 0; mf < 4; ++mf)
#pragma unroll
        for (int nf = 0; nf < 4; ++nf)
          acc[mf][nf] = mfma_bf16(af[mf], bf[nf], acc[mf][nf]);
    }
  }
#pragma unroll
  for (int mf = 0; mf < 4; ++mf)
#pragma unroll
    for (int nf = 0; nf < 4; ++nf)
#pragma unroll
      for (int r = 0; r < 4; ++r) {
        int m = m0 + wm * 64 + mf * 16 + g * 4 + r;
        int n = n0 + wn * 64 + nf * 16 + i16;
        if (OUTF32)
          Cf[(size_t)m * N + n] = acc[mf][nf][r] * oscale;
        else
          Cb[(size_t)m * N + n] = f2bf(acc[mf][nf][r] * oscale);
      }
}

// ---------------- fused flash attention: 64 q-rows/wave, zero LDS, K double-buffered ----------------
// Q (pre-scaled by 0.125*log2e), K: [8192,1024] bf16; Vt: [64*64,2048] bf16; O: [8192,1024] bf16
__device__ __forceinline__ void attn_body(int kt, const u16* __restrict__ Kbase,
                                          const u16* __restrict__ Vbase,
                                          vshort8 (&kfc)[2][4], vshort8 (&kfn)[2][4],
                                          vshort8 (&qf)[2][4], vf32x16 (&oacc)[2][2],
                                          float (&mrun)[2], float (&lrun)[2],
                                          int l31, int hi) {
  int ktn = kt + 1 < 32 ? kt + 1 : 31;
  // prefetch next K tile (consumed next body; latency hidden under this body's chain)
#pragma unroll
  for (int ks = 0; ks < 2; ++ks)
#pragma unroll
    for (int dc = 0; dc < 4; ++dc)
      kfn[ks][dc] = *(const vshort8*)&Kbase[(size_t)(ktn * 64 + ks * 32 + l31) * 1024 + dc * 16 + hi * 8];

  unsigned pk[2][2][8];
#pragma unroll
  for (int fq = 0; fq < 2; ++fq) {
    // S^T = K·Q for this q-half
    vf32x16 sacc[2];
#pragma unroll
    for (int ks = 0; ks < 2; ++ks)
#pragma unroll
      for (int r = 0; r < 16; ++r) sacc[ks][r] = 0.f;
    __builtin_amdgcn_s_setprio(1);
#pragma unroll
    for (int dc = 0; dc < 4; ++dc)
#pragma unroll
      for (int ks = 0; ks < 2; ++ks)
        sacc[ks] = mfma32(kfc[ks][dc], qf[fq][dc], sacc[ks]);
    __builtin_amdgcn_s_setprio(0);

    // tree max over the 32 in-lane values + one cross-half swap
    float tm[8];
#pragma unroll
    for (int r = 0; r < 8; ++r)
      tm[r] = fmaxf(fmaxf(sacc[0][r], sacc[0][r + 8]), fmaxf(sacc[1][r], sacc[1][r + 8]));
#pragma unroll
    for (int r = 0; r < 4; ++r) tm[r] = fmaxf(tm[r], tm[r + 4]);
    float pmax = fmaxf(fmaxf(tm[0], tm[1]), fmaxf(tm[2], tm[3]));
    pmax = fmaxf(pmax, swap32f(pmax));

    if (pmax > mrun[fq] + 8.f) {  // defer-max
      float al = exp2f(mrun[fq] - pmax);
      lrun[fq] *= al;
#pragma unroll
      for (int dm = 0; dm < 2; ++dm)
#pragma unroll
        for (int r = 0; r < 16; ++r) oacc[dm][fq][r] *= al;
      mrun[fq] = pmax;
    }
    float mm = mrun[fq];

    // exp2 + pack + per-lane partial sum (cross-half sum deferred to epilogue)
    float s0 = 0.f, s1 = 0.f, s2 = 0.f, s3 = 0.f;
#pragma unroll
    for (int ks = 0; ks < 2; ++ks)
#pragma unroll
      for (int u = 0; u < 8; ++u) {
        float p0 = exp2f(sacc[ks][2 * u] - mm);
        float p1 = exp2f(sacc[ks][2 * u + 1] - mm);
        pk[fq][ks][u] = cvtpk(p0, p1);
        if (u & 1) { s0 += p0; s1 += p1; } else { s2 += p0; s3 += p1; }
      }
    lrun[fq] += (s0 + s1) + (s2 + s3);
  }

  // V^T fragments for current tile (issued here, consumed just below)
  vshort8 vtf[2][4];
#pragma unroll
  for (int dm = 0; dm < 2; ++dm)
#pragma unroll
    for (int s = 0; s < 4; ++s)
      vtf[dm][s] = *(const vshort8*)&Vbase[(size_t)(dm * 32 + l31) * 2048 + kt * 64 + s * 16 + hi * 8];

  // in-register P redistribution + PV
#pragma unroll
  for (int s = 0; s < 4; ++s) {
    vshort8 pb[2];
    const int ks = s >> 1, s1b = s & 1;
#pragma unroll
    for (int fq = 0; fq < 2; ++fq) {
      unsigned wA0 = pk[fq][ks][4 * s1b + 0], wA1 = pk[fq][ks][4 * s1b + 1];
      unsigned wB0 = pk[fq][ks][4 * s1b + 2], wB1 = pk[fq][ks][4 * s1b + 3];
      unsigned sA0 = hi ? wB0 : wA0, sA1 = hi ? wB1 : wA1;
      unsigned sd0 = hi ? wA0 : wB0, sd1 = hi ? wA1 : wB1;
      unsigned rv0 = __shfl_xor((int)sd0, 32), rv1 = __shfl_xor((int)sd1, 32);
      uint4 wv;
      wv.x = hi ? rv0 : sA0; wv.y = hi ? rv1 : sA1;
      wv.z = hi ? sA0 : rv0; wv.w = hi ? sA1 : rv1;
      pb[fq] = __builtin_bit_cast(vshort8, wv);
    }
    __builtin_amdgcn_s_setprio(1);
#pragma unroll
    for (int dm = 0; dm < 2; ++dm)
#pragma unroll
      for (int fq = 0; fq < 2; ++fq)
        oacc[dm][fq] = mfma32(vtf[dm][s], pb[fq], oacc[dm][fq]);
    __builtin_amdgcn_s_setprio(0);
  }
}

__global__ __launch_bounds__(512, 2) void attn_fwd4(const u16* __restrict__ Q,
                                                    const u16* __restrict__ K,
                                                    const u16* __restrict__ Vt,
                                                    u16* __restrict__ O) {
  int t = threadIdx.x, lane = t & 63, w = t >> 6;
  int l31 = lane & 31, hi = lane >> 5;
  int i = blockIdx.x;                    // 256 blocks
  int qb = (i >> 3) & 3;
  int bh = (i & 7) + 8 * (i >> 5);       // same-bh blocks share XCD
  int b = bh >> 4, h = bh & 15;

  const u16* Qbase = Q + (size_t)(b * 2048 + qb * 512 + w * 64) * 1024 + h * 64;
  const u16* Kbase = K + (size_t)(b * 2048) * 1024 + h * 64;
  const u16* Vbase = Vt + (size_t)(bh * 64) * 2048;

  vshort8 qf[2][4];
#pragma unroll
  for (int fq = 0; fq < 2; ++fq)
#pragma unroll
    for (int dc = 0; dc < 4; ++dc)
      qf[fq][dc] = *(const vshort8*)&Qbase[(size_t)(fq * 32 + l31) * 1024 + dc * 16 + hi * 8];

  vf32x16 oacc[2][2];
#pragma unroll
  for (int dm = 0; dm < 2; ++dm)
#pragma unroll
    for (int fq = 0; fq < 2; ++fq)
#pragma unroll
      for (int r = 0; r < 16; ++r) oacc[dm][fq][r] = 0.f;
  float mrun[2] = {-3.0e38f, -3.0e38f}, lrun[2] = {0.f, 0.f};

  // initial K tile
  vshort8 kfA[2][4], kfB[2][4];
#pragma unroll
  for (int ks = 0; ks < 2; ++ks)
#pragma unroll
    for (int dc = 0; dc < 4; ++dc)
      kfA[ks][dc] = *(const vshort8*)&Kbase[(size_t)(ks * 32 + l31) * 1024 + dc * 16 + hi * 8];

  for (int kt = 0; kt < 32; kt += 2) {
    attn_body(kt,     Kbase, Vbase, kfA, kfB, qf, oacc, mrun, lrun, l31, hi);
    attn_body(kt + 1, Kbase, Vbase, kfB, kfA, qf, oacc, mrun, lrun, l31, hi);
  }

  // epilogue: cross-half sum of lrun, normalize, store
#pragma unroll
  for (int fq = 0; fq < 2; ++fq) {
    float lt = lrun[fq] + swap32f(lrun[fq]);
    float inv = 1.f / lt;
    size_t qrow = (size_t)(b * 2048 + qb * 512 + w * 64 + fq * 32 + l31);
#pragma unroll
    for (int dm = 0; dm < 2; ++dm)
#pragma unroll
      for (int u = 0; u < 4; ++u) {
        unsigned w0 = cvtpk(oacc[dm][fq][4 * u + 0] * inv, oacc[dm][fq][4 * u + 1] * inv);
        unsigned w1 = cvtpk(oacc[dm][fq][4 * u + 2] * inv, oacc[dm][fq][4 * u + 3] * inv);
        uint2 o; o.x = w0; o.y = w1;
        *(uint2*)&O[qrow * 1024 + h * 64 + dm * 32 + 8 * u + 4 * hi] = o;
      }
  }
}

extern "C" void kernel_launch(void* const* d_in, const int* in_sizes, int n_in,
                              void* d_out, int out_size, void* d_ws, size_t ws_size,
                              hipStream_t stream) {
  const float* q  = (const float*)d_in[0];
  const float* k  = (const float*)d_in[1];
  const float* v  = (const float*)d_in[2];
  const float* wq = (const float*)d_in[3];
  const float* wk = (const float*)d_in[4];
  const float* wv = (const float*)d_in[5];
  const float* wo = (const float*)d_in[6];
  float* out = (float*)d_out;

  const int M = 8192, D = 1024;
  u16* Qb = (u16*)d_out;                // Q,K (bf16) parked in d_out (32MB)
  u16* Kb = Qb + (size_t)M * D;
  u16* xb  = (u16*)d_ws;                // staging / attn-out
  u16* Vb  = xb + (size_t)M * D;
  u16* Vtg = Vb + (size_t)M * D;        // doubles as xk staging before vtrans
  u16* wqt = Vtg + (size_t)M * D;
  u16* wkt = wqt + (size_t)D * D;
  u16* wvt = wkt + (size_t)D * D;
  u16* wot = wvt + (size_t)D * D;

  dim3 blk(256);
  wtrans4<<<dim3(16, 16, 4), blk, 0, stream>>>(wq, wk, wv, wo, wqt, wkt, wvt, wot);

  const float QSCALE = 0.125f * 1.44269504088896f;  // 1/sqrt(64) * log2(e)
  int n4 = M * D / 4;
  dim3 ggemm(8, 64);
  cvtk2<<<dim3(1024, 2), blk, 0, stream>>>(q, k, xb, Vtg, n4);
  gemm_nt<0><<<ggemm, blk, 0, stream>>>(xb, wqt, nullptr, Qb, M, D, D, QSCALE);
  gemm_nt<0><<<ggemm, blk, 0, stream>>>(Vtg, wkt, nullptr, Kb, M, D, D, 1.0f);
  cvtk2<<<dim3(1024, 1), blk, 0, stream>>>(v, nullptr, xb, nullptr, n4);
  gemm_nt<0><<<ggemm, blk, 0, stream>>>(xb, wvt, nullptr, Vb, M, D, D, 1.0f);

  vtrans<<<dim3(32, 64), blk, 0, stream>>>(Vb, Vtg);
  attn_fwd4<<<dim3(256), dim3(512), 0, stream>>>(Qb, Kb, Vtg, xb /* -> attn out */);
  gemm_nt<1><<<ggemm, blk, 0, stream>>>(xb, wot, out, nullptr, M, D, D, 1.0f);
}